// Round 1
// baseline (432.178 us; speedup 1.0000x reference)
//
#include <hip/hip_runtime.h>
#include <math.h>

// SoftAttentionAggregator — round 6: barrier-free pipelined staging + no-ws.
//
// Deduction from rocprof: no timed dispatch exceeds ~158 us but dur=400 us ->
// timed region = 2x 1-GiB fillBufferAligned (workspace re-poison, ~314 us) +
// prep + main (~84 us). Two attacks in this round:
//  (A) main kernel: phase-1 was 16x {width-4 DMA, __syncthreads}; each barrier
//      drains vmcnt(0), exposing ~900 cy HBM latency per chunk. Replaced by a
//      wave-private 3-buffer pipeline (32 chunks x 8 channels), width-16
//      global_load_lds, counted s_waitcnt vmcnt(2), ZERO barriers in phase 1
//      (each wave converts exactly the rows it DMA'd itself).
//  (B) dur_us: drop d_ws + prep_kernel entirely (A-frags converted from fp32
//      w1 inline via v_cvt_pk_bf16_f32, identical RNE) to test whether the
//      1-GiB poison fills are conditional on workspace use.
// Tile layout: stride-128 dwords with per-row granule XOR swizzle
// (granule ^= n&7). GEMM b128 reads and pooling reads stay conflict-free;
// saves 2 KB LDS vs stride-132. s_lg/s_wt overlay s_raw (dead after phase 1),
// valid mask kept in a register. LDS total 81,472 B -> 2 blocks/CU.

#define B_ 8
#define H_ 256
#define P_ 1024
#define K_ 32
#define E_ 4
#define BN_ 64

typedef __attribute__((ext_vector_type(8))) short short8;
typedef __attribute__((ext_vector_type(4))) float floatx4;

__device__ __forceinline__ unsigned short bf16_rne(float f) {
  unsigned u = __float_as_uint(f);
  u += 0x7fffu + ((u >> 16) & 1u);
  return (unsigned short)(u >> 16);
}
// HW packed f32->bf16 RNE: D[15:0]=cvt(lo), D[31:16]=cvt(hi).
__device__ __forceinline__ unsigned pack_bf16(float lo, float hi) {
  unsigned r;
  asm("v_cvt_pk_bf16_f32 %0, %1, %2" : "=v"(r) : "v"(lo), "v"(hi));
  return r;
}

// async global->LDS, 16 B per lane: per-lane global addr, LDS gets
// wave-uniform base + lane*16.
__device__ __forceinline__ void async_cp16(const float* g, float* l) {
  __builtin_amdgcn_global_load_lds(
      (const __attribute__((address_space(1))) unsigned*)g,
      (__attribute__((address_space(3))) unsigned*)l, 16, 0, 0);
}

// Swizzled tile addressing: logical (n, cp) -> dword index.
// Row stride 128 dwords; 4-dword granule g = cp>>2 is XOR'd with (n&7).
// - GEMM b128 reads (granule-aligned): 2-way max (free).
// - pooling reads (consecutive cp per lane): conflict-free.
// - conversion column writes: 8-way (acceptable; off critical path).
__device__ __forceinline__ unsigned* tile_ptr(unsigned* tile, int n, int cp) {
  return tile + n * 128 + ((((cp >> 2) ^ (n & 7)) << 2) | (cp & 3));
}

#define STR_(x) #x
#define VMWAIT(n) asm volatile("s_waitcnt vmcnt(" STR_(n) ")")

__global__ __launch_bounds__(256, 2) void soft_attn_agg_kernel(
    const float* __restrict__ cur,   // (B,H,P)
    const float* __restrict__ nf,    // (B,H,P,K)
    const float* __restrict__ nv,    // (B,1,P,K)
    const float* __restrict__ ef,    // (B,E,P,K)
    const float* __restrict__ w1,    // (64,516) fp32, L2-hot
    const float* __restrict__ b1,    // (64)
    const float* __restrict__ w2,    // (64)
    float* __restrict__ out) {       // (B,H,P)
  __shared__ unsigned s_tile[128 * 128];   // 64 KB bf16 c-pair tile, swizzled
  __shared__ float s_raw[3 * 8 * 128];     // 12 KB fp32 DMA triple-buffer
  __shared__ unsigned short s_curb[4][264];  // bf16 cur [pl][c]
  __shared__ unsigned s_edge[4][32][2];      // [pl][k][e01,e23]
  __shared__ float s_b1v[BN_];
  __shared__ float s_w2v[BN_];
  // s_raw is dead after the phase-1 barrier; reuse for logits/weights.
  float* const s_lg = s_raw;         // [128]
  float* const s_wt = s_raw + 128;   // [128]

  const int t = threadIdx.x;
  const unsigned bid = blockIdx.x;
  const unsigned xcd = bid & 7u, sx = bid >> 3;
  const int b = (int)(sx >> 5);
  const int pg = (int)(xcd * 32u + (sx & 31u));  // 0..255
  const int p0 = pg * 4;

  const int w = t >> 6;     // wave 0..3
  const int lane = t & 63;
  const int q = lane >> 4;  // quad
  const int ln15 = lane & 15;

  const float* nf_b = nf + ((size_t)b * H_ * P_ + p0) * K_;

  // One width-16 DMA per wave per chunk: lanes 0..31 -> row (2w), lanes
  // 32..63 -> row (2w+1) of the 8-row chunk buffer (rows contiguous in LDS).
#define ISSUE_DMA(ch, bufbase)                                               \
  async_cp16(nf_b + (size_t)((ch)*8 + 2 * w + (lane >> 5)) * (P_ * K_) +     \
                 ((lane & 31) << 2),                                         \
             (bufbase) + 2 * w * 128)

  float* const rbuf0 = s_raw;
  float* const rbuf1 = s_raw + 1024;
  float* const rbuf2 = s_raw + 2048;

  // ---- DMA prologue: chunks 0..2 in flight before anything else ----
  ISSUE_DMA(0, rbuf0);
  ISSUE_DMA(1, rbuf1);
  ISSUE_DMA(2, rbuf2);

  // ---- small staging (normal loads; overlap the first DMA latency) ----
  {
    const float* cb = cur + ((size_t)b * H_ + t) * P_ + p0;
    float4 ca = *(const float4*)cb;
    s_curb[0][t] = bf16_rne(ca.x);
    s_curb[1][t] = bf16_rne(ca.y);
    s_curb[2][t] = bf16_rne(ca.z);
    s_curb[3][t] = bf16_rne(ca.w);
  }
  float my_valid = 0.f;
  if (t < 128) {
    my_valid = nv[((size_t)b * P_ + p0) * K_ + t];
    const int pl = t >> 5, k = t & 31;
    const float* ep = ef + ((size_t)b * E_ * P_ + p0 + pl) * K_ + k;
    float e0 = ep[0];
    float e1 = ep[(size_t)(P_ * K_)];
    float e2 = ep[(size_t)(2 * P_ * K_)];
    float e3 = ep[(size_t)(3 * P_ * K_)];
    s_edge[pl][k][0] = pack_bf16(e0, e1);
    s_edge[pl][k][1] = pack_bf16(e2, e3);
  } else if (t < 192) {
    s_b1v[t - 128] = b1[t - 128];
  } else {
    s_w2v[t - 192] = w2[t - 192];
  }

  // ---- Phase 1: barrier-free wave-private pipeline over 32 chunks ----
  // Iteration ch: wait own DMA[ch] (counted vmcnt), read own 2 rows, pack,
  // then (reads retired -> sched_barrier) issue DMA[ch+3] into the same
  // buffer, then write the c-pair column into the swizzled tile.
#define PIPE_ITER(ch, bufbase, VMN, DO_ISSUE)                                \
  {                                                                          \
    VMWAIT(VMN);                                                             \
    __builtin_amdgcn_sched_barrier(0);                                       \
    const float* rb0 = (bufbase) + 2 * w * 128;                              \
    const float* rb1 = rb0 + 128;                                            \
    float fe0 = rb0[lane], fo0 = rb1[lane];                                  \
    float fe1 = rb0[lane + 64], fo1 = rb1[lane + 64];                        \
    unsigned pk0 = pack_bf16(fe0, fo0);                                      \
    unsigned pk1 = pack_bf16(fe1, fo1);                                      \
    __builtin_amdgcn_sched_barrier(0);                                       \
    if (DO_ISSUE) ISSUE_DMA((ch) + 3, bufbase);                              \
    const int cpv = 4 * (ch) + w;                                            \
    *tile_ptr(s_tile, lane, cpv) = pk0;                                      \
    *tile_ptr(s_tile, lane + 64, cpv) = pk1;                                 \
  }

  for (int c3 = 0; c3 < 30; c3 += 3) {
    PIPE_ITER(c3, rbuf0, 2, (c3) < 29);
    PIPE_ITER(c3 + 1, rbuf1, 2, (c3 + 1) < 29);
    PIPE_ITER(c3 + 2, rbuf2, 2, (c3 + 2) < 29);
  }
  PIPE_ITER(30, rbuf0, 1, false);
  PIPE_ITER(31, rbuf1, 0, false);
  __syncthreads();  // tile + curb/edge/b1/w2 complete for all waves

  // ---- Phase 2: GEMM hid[64 x 128] = W1[64x516+pad] * Z[...x128].
  // A-frags converted inline from fp32 w1 (L2-hot) — no workspace.
  floatx4 acc[4][2];
#pragma unroll
  for (int mt = 0; mt < 4; ++mt) {
    floatx4 binit = *(const floatx4*)&s_b1v[mt * 16 + q * 4];
    acc[mt][0] = binit;
    acc[mt][1] = binit;
  }
  const float* w1base = w1 + (size_t)ln15 * 516 + q * 8;

  // cur chunks (Z rows 0..255): b-frag independent of k -> shared by both nt
#pragma unroll
  for (int ki = 0; ki < 8; ++ki) {
    short8 bc = *(const short8*)&s_curb[w][ki * 32 + q * 8];
#pragma unroll
    for (int mt = 0; mt < 4; ++mt) {
      const float* ap = w1base + (size_t)mt * (16 * 516) + ki * 32;
      float4 f0 = *(const float4*)ap;
      float4 f1 = *(const float4*)(ap + 4);
      union { unsigned u[4]; short8 s; } a;
      a.u[0] = pack_bf16(f0.x, f0.y);
      a.u[1] = pack_bf16(f0.z, f0.w);
      a.u[2] = pack_bf16(f1.x, f1.y);
      a.u[3] = pack_bf16(f1.z, f1.w);
      acc[mt][0] = __builtin_amdgcn_mfma_f32_16x16x32_bf16(a.s, bc, acc[mt][0], 0, 0, 0);
      acc[mt][1] = __builtin_amdgcn_mfma_f32_16x16x32_bf16(a.s, bc, acc[mt][1], 0, 0, 0);
    }
  }
  // nf chunks (Z rows 256..511): b128 tile reads (swizzled, conflict-free)
#pragma unroll
  for (int ck = 0; ck < 8; ++ck) {
    short8 bn0 = *(const short8*)tile_ptr(s_tile, 32 * w + ln15, (4 * ck + q) << 2);
    short8 bn1 = *(const short8*)tile_ptr(s_tile, 32 * w + 16 + ln15, (4 * ck + q) << 2);
#pragma unroll
    for (int mt = 0; mt < 4; ++mt) {
      const float* ap = w1base + (size_t)mt * (16 * 516) + 256 + ck * 32;
      float4 f0 = *(const float4*)ap;
      float4 f1 = *(const float4*)(ap + 4);
      union { unsigned u[4]; short8 s; } a;
      a.u[0] = pack_bf16(f0.x, f0.y);
      a.u[1] = pack_bf16(f0.z, f0.w);
      a.u[2] = pack_bf16(f1.x, f1.y);
      a.u[3] = pack_bf16(f1.z, f1.w);
      acc[mt][0] = __builtin_amdgcn_mfma_f32_16x16x32_bf16(a.s, bn0, acc[mt][0], 0, 0, 0);
      acc[mt][1] = __builtin_amdgcn_mfma_f32_16x16x32_bf16(a.s, bn1, acc[mt][1], 0, 0, 0);
    }
  }
  // edge chunk (Z rows 512..515; A cols >=516 zero -> B tail don't-care)
  {
    union { unsigned u[4]; short8 s; } ub0, ub1;
    *(uint2*)&ub0.u[0] = *(const uint2*)&s_edge[w][ln15][0];
    ub0.u[2] = 0u; ub0.u[3] = 0u;
    *(uint2*)&ub1.u[0] = *(const uint2*)&s_edge[w][16 + ln15][0];
    ub1.u[2] = 0u; ub1.u[3] = 0u;
#pragma unroll
    for (int mt = 0; mt < 4; ++mt) {
      union { unsigned u[4]; short8 s; } ae;
      if (q == 0) {  // A cols 512..515 valid, 516..519 zero
        const float* ap = w1 + (size_t)(mt * 16 + ln15) * 516 + 512;
        float4 f0 = *(const float4*)ap;
        ae.u[0] = pack_bf16(f0.x, f0.y);
        ae.u[1] = pack_bf16(f0.z, f0.w);
      } else {
        ae.u[0] = 0u; ae.u[1] = 0u;
      }
      ae.u[2] = 0u; ae.u[3] = 0u;
      acc[mt][0] = __builtin_amdgcn_mfma_f32_16x16x32_bf16(ae.s, ub0.s, acc[mt][0], 0, 0, 0);
      acc[mt][1] = __builtin_amdgcn_mfma_f32_16x16x32_bf16(ae.s, ub1.s, acc[mt][1], 0, 0, 0);
    }
  }

  // ---- Phase 3: relu, dot w2, fold rows -> logit per column n
#pragma unroll
  for (int nti = 0; nti < 2; ++nti) {
    float lp = 0.f;
#pragma unroll
    for (int mt = 0; mt < 4; ++mt) {
      const floatx4 w2v = *(const floatx4*)&s_w2v[mt * 16 + q * 4];
#pragma unroll
      for (int r = 0; r < 4; ++r)
        lp = fmaf(fmaxf(acc[mt][nti][r], 0.f), w2v[r], lp);
    }
    lp += __shfl_xor(lp, 16);
    lp += __shfl_xor(lp, 32);
    if (lane < 16) s_lg[(2 * w + nti) * 16 + ln15] = lp;
  }
  __syncthreads();

  // ---- Phase 4: masked softmax per p over K=32 (threads 0..127)
  if (t < 128) {
    float lg = s_lg[t];
    bool v = my_valid > 0.5f;
    float ml = v ? lg : -INFINITY;
#pragma unroll
    for (int m = 1; m < 32; m <<= 1) ml = fmaxf(ml, __shfl_xor(ml, m));
    float e = v ? __expf(lg - ml) : 0.f;
    float ssum = e;
#pragma unroll
    for (int m = 1; m < 32; m <<= 1) ssum += __shfl_xor(ssum, m);
    s_wt[t] = (ml > -INFINITY) ? (e / ssum) : 0.f;
  }
  __syncthreads();

  // ---- Phase 5: pooling. Thread t -> (cpr = t&127, p-pair ph = t>>7).
  {
    const int cpr = t & 127, ph = t >> 7;
    const int nb = ph * 64;  // n base for p_local = 2ph
    float a0e = 0.f, a0o = 0.f, a1e = 0.f, a1o = 0.f;
#pragma unroll
    for (int k = 0; k < K_; ++k) {
      const unsigned u0 = *tile_ptr(s_tile, nb + k, cpr);
      const unsigned u1 = *tile_ptr(s_tile, nb + 32 + k, cpr);
      const float wt0 = s_wt[nb + k];
      const float wt1 = s_wt[nb + 32 + k];
      a0e = fmaf(__uint_as_float(u0 << 16), wt0, a0e);
      a0o = fmaf(__uint_as_float(u0 & 0xffff0000u), wt0, a0o);
      a1e = fmaf(__uint_as_float(u1 << 16), wt1, a1e);
      a1o = fmaf(__uint_as_float(u1 & 0xffff0000u), wt1, a1o);
    }
    float* op = out + ((size_t)b * H_ + 2 * cpr) * P_ + p0 + 2 * ph;
    float2 ve; ve.x = a0e; ve.y = a1e;   // c even: p_local = 2ph, 2ph+1
    float2 vo; vo.x = a0o; vo.y = a1o;   // c odd
    *(float2*)op = ve;
    *(float2*)(op + P_) = vo;
  }
}

extern "C" void kernel_launch(void* const* d_in, const int* in_sizes, int n_in,
                              void* d_out, int out_size, void* d_ws,
                              size_t ws_size, hipStream_t stream) {
  const float* cur = (const float*)d_in[0];
  const float* nf  = (const float*)d_in[1];
  const float* nv  = (const float*)d_in[2];
  const float* ef  = (const float*)d_in[3];
  const float* w1  = (const float*)d_in[4];
  const float* b1  = (const float*)d_in[5];
  const float* w2  = (const float*)d_in[6];
  // d_in[7] = b2: softmax shift-invariant -> never affects output.
  // d_ws intentionally UNUSED this round (tests poison-fill hypothesis).
  (void)d_ws; (void)ws_size;

  soft_attn_agg_kernel<<<B_ * P_ / 4, 256, 0, stream>>>(
      cur, nf, nv, ef, w1, b1, w2, (float*)d_out);
}

// Round 2
// 399.639 us; speedup vs baseline: 1.0814x; 1.0814x over previous
//
#include <hip/hip_runtime.h>
#include <math.h>

// SoftAttentionAggregator — round 7: restore packed-w1m phase 2, keep
// barrier-free pipelined phase 1.
//
// Round-1 lesson: (a) the 1-GiB workspace poison fills are paid whether or
// not d_ws is used (400 -> 432 when unused) => workspace is free, use it.
// (b) inline fp32-w1 conversion in phase 2 was a 2x main-kernel regression:
// scattered per-lane float4 loads (~32 x 64B segments/instr, x4 waves, L1
// thrash) ~8x the L2 traffic of the coalesced bf16 w1m path. Reverted.
// Kept from round 1 (theory-sound, now isolated for measurement):
//  - phase-1 barrier-free depth-3 DMA pipeline: 32 chunks x 8 channels,
//    width-16 global_load_lds, counted s_waitcnt vmcnt(2), zero barriers
//    (each wave converts exactly the rows it DMA'd itself).
//  - swizzled stride-128 tile (64 KB), s_lg/s_wt overlay s_raw, valid in reg.
// LDS total 81,472 B -> 2 blocks/CU.

#define B_ 8
#define H_ 256
#define P_ 1024
#define K_ 32
#define E_ 4
#define BN_ 64

typedef __attribute__((ext_vector_type(8))) short short8;
typedef __attribute__((ext_vector_type(4))) float floatx4;

__device__ __forceinline__ unsigned short bf16_rne(float f) {
  unsigned u = __float_as_uint(f);
  u += 0x7fffu + ((u >> 16) & 1u);
  return (unsigned short)(u >> 16);
}
// HW packed f32->bf16 RNE: D[15:0]=cvt(lo), D[31:16]=cvt(hi).
__device__ __forceinline__ unsigned pack_bf16(float lo, float hi) {
  unsigned r;
  asm("v_cvt_pk_bf16_f32 %0, %1, %2" : "=v"(r) : "v"(lo), "v"(hi));
  return r;
}

// async global->LDS, 16 B per lane: per-lane global addr, LDS gets
// wave-uniform base + lane*16.
__device__ __forceinline__ void async_cp16(const float* g, float* l) {
  __builtin_amdgcn_global_load_lds(
      (const __attribute__((address_space(1))) unsigned*)g,
      (__attribute__((address_space(3))) unsigned*)l, 16, 0, 0);
}

// Swizzled tile addressing: logical (n, cp) -> dword index.
// Row stride 128 dwords; 4-dword granule g = cp>>2 is XOR'd with (n&7).
// - GEMM b128 reads (granule-aligned): 2-way max (free).
// - pooling reads (consecutive cp per lane): conflict-free.
// - conversion column writes: 8-way (small, off critical path).
__device__ __forceinline__ unsigned* tile_ptr(unsigned* tile, int n, int cp) {
  return tile + n * 128 + ((((cp >> 2) ^ (n & 7)) << 2) | (cp & 3));
}

#define STR_(x) #x
#define VMWAIT(n) asm volatile("s_waitcnt vmcnt(" STR_(n) ")")

// Pack w1 (64x516) into bf16 MFMA A-frag layout:
// idx = ((mt*17 + ki)*64 + lane)*8 + j ; o = mt*16 + (lane&15),
// c = ki*32 + (lane>>4)*8 + j ; zero-pad c >= 516.
__global__ __launch_bounds__(256) void prep_kernel(
    const float* __restrict__ w1, unsigned short* __restrict__ w1m) {
  int i = blockIdx.x * 256 + threadIdx.x;
  if (i >= 4 * 17 * 64 * 8) return;  // 34816
  int j = i & 7, lane = (i >> 3) & 63;
  int kt = i >> 9;
  int mt = kt / 17, ki = kt % 17;
  int o = mt * 16 + (lane & 15);
  int c = ki * 32 + (lane >> 4) * 8 + j;
  float v = (c < 516) ? w1[o * 516 + c] : 0.f;
  w1m[i] = bf16_rne(v);
}

__global__ __launch_bounds__(256, 2) void soft_attn_agg_kernel(
    const float* __restrict__ cur,   // (B,H,P)
    const float* __restrict__ nf,    // (B,H,P,K)
    const float* __restrict__ nv,    // (B,1,P,K)
    const float* __restrict__ ef,    // (B,E,P,K)
    const unsigned short* __restrict__ w1m,  // packed A-frags (68 KB, L2-hot)
    const float* __restrict__ b1,    // (64)
    const float* __restrict__ w2,    // (64)
    float* __restrict__ out) {       // (B,H,P)
  __shared__ unsigned s_tile[128 * 128];   // 64 KB bf16 c-pair tile, swizzled
  __shared__ float s_raw[3 * 8 * 128];     // 12 KB fp32 DMA triple-buffer
  __shared__ unsigned short s_curb[4][264];  // bf16 cur [pl][c]
  __shared__ unsigned s_edge[4][32][2];      // [pl][k][e01,e23]
  __shared__ float s_b1v[BN_];
  __shared__ float s_w2v[BN_];
  // s_raw is dead after the phase-1 barrier; reuse for logits/weights.
  float* const s_lg = s_raw;         // [128]
  float* const s_wt = s_raw + 128;   // [128]

  const int t = threadIdx.x;
  const unsigned bid = blockIdx.x;
  const unsigned xcd = bid & 7u, sx = bid >> 3;
  const int b = (int)(sx >> 5);
  const int pg = (int)(xcd * 32u + (sx & 31u));  // 0..255
  const int p0 = pg * 4;

  const int w = t >> 6;     // wave 0..3
  const int lane = t & 63;
  const int q = lane >> 4;  // quad
  const int ln15 = lane & 15;

  const float* nf_b = nf + ((size_t)b * H_ * P_ + p0) * K_;

  // One width-16 DMA per wave per chunk: lanes 0..31 -> row (2w), lanes
  // 32..63 -> row (2w+1) of the 8-row chunk buffer (rows contiguous in LDS).
#define ISSUE_DMA(ch, bufbase)                                               \
  async_cp16(nf_b + (size_t)((ch)*8 + 2 * w + (lane >> 5)) * (P_ * K_) +     \
                 ((lane & 31) << 2),                                         \
             (bufbase) + 2 * w * 128)

  float* const rbuf0 = s_raw;
  float* const rbuf1 = s_raw + 1024;
  float* const rbuf2 = s_raw + 2048;

  // ---- DMA prologue: chunks 0..2 in flight before anything else ----
  ISSUE_DMA(0, rbuf0);
  ISSUE_DMA(1, rbuf1);
  ISSUE_DMA(2, rbuf2);

  // ---- small staging (normal loads; overlap the first DMA latency) ----
  {
    const float* cb = cur + ((size_t)b * H_ + t) * P_ + p0;
    float4 ca = *(const float4*)cb;
    s_curb[0][t] = bf16_rne(ca.x);
    s_curb[1][t] = bf16_rne(ca.y);
    s_curb[2][t] = bf16_rne(ca.z);
    s_curb[3][t] = bf16_rne(ca.w);
  }
  float my_valid = 0.f;
  if (t < 128) {
    my_valid = nv[((size_t)b * P_ + p0) * K_ + t];
    const int pl = t >> 5, k = t & 31;
    const float* ep = ef + ((size_t)b * E_ * P_ + p0 + pl) * K_ + k;
    float e0 = ep[0];
    float e1 = ep[(size_t)(P_ * K_)];
    float e2 = ep[(size_t)(2 * P_ * K_)];
    float e3 = ep[(size_t)(3 * P_ * K_)];
    s_edge[pl][k][0] = pack_bf16(e0, e1);
    s_edge[pl][k][1] = pack_bf16(e2, e3);
  } else if (t < 192) {
    s_b1v[t - 128] = b1[t - 128];
  } else {
    s_w2v[t - 192] = w2[t - 192];
  }

  // ---- Phase 1: barrier-free wave-private pipeline over 32 chunks ----
  // Iteration ch: wait own DMA[ch] (counted vmcnt), read own 2 rows, pack,
  // then (reads retired -> sched_barrier) issue DMA[ch+3] into the same
  // buffer, then write the c-pair column into the swizzled tile.
#define PIPE_ITER(ch, bufbase, VMN, DO_ISSUE)                                \
  {                                                                          \
    VMWAIT(VMN);                                                             \
    __builtin_amdgcn_sched_barrier(0);                                       \
    const float* rb0 = (bufbase) + 2 * w * 128;                              \
    const float* rb1 = rb0 + 128;                                            \
    float fe0 = rb0[lane], fo0 = rb1[lane];                                  \
    float fe1 = rb0[lane + 64], fo1 = rb1[lane + 64];                        \
    unsigned pk0 = pack_bf16(fe0, fo0);                                      \
    unsigned pk1 = pack_bf16(fe1, fo1);                                      \
    __builtin_amdgcn_sched_barrier(0);                                       \
    if (DO_ISSUE) ISSUE_DMA((ch) + 3, bufbase);                              \
    const int cpv = 4 * (ch) + w;                                            \
    *tile_ptr(s_tile, lane, cpv) = pk0;                                      \
    *tile_ptr(s_tile, lane + 64, cpv) = pk1;                                 \
  }

  for (int c3 = 0; c3 < 30; c3 += 3) {
    PIPE_ITER(c3, rbuf0, 2, (c3) < 29);
    PIPE_ITER(c3 + 1, rbuf1, 2, (c3 + 1) < 29);
    PIPE_ITER(c3 + 2, rbuf2, 2, (c3 + 2) < 29);
  }
  PIPE_ITER(30, rbuf0, 1, false);
  PIPE_ITER(31, rbuf1, 0, false);
  __syncthreads();  // tile + curb/edge/b1/w2 complete for all waves

  // ---- Phase 2: GEMM hid[64 x 128] = W1[64x544] * Z[544x128] via
  // mfma_f32_16x16x32_bf16, A-frags from packed w1m (coalesced 1 KB loads).
  floatx4 acc[4][2];
#pragma unroll
  for (int mt = 0; mt < 4; ++mt) {
    floatx4 binit = *(const floatx4*)&s_b1v[mt * 16 + q * 4];
    acc[mt][0] = binit;
    acc[mt][1] = binit;
  }
  const unsigned short* w1m_l = w1m + (size_t)lane * 8;

  // cur chunks (Z rows 0..255): b-frag independent of k -> shared by both nt
#pragma unroll
  for (int ki = 0; ki < 8; ++ki) {
    short8 bc = *(const short8*)&s_curb[w][ki * 32 + q * 8];
#pragma unroll
    for (int mt = 0; mt < 4; ++mt) {
      short8 a = *(const short8*)(w1m_l + (size_t)(mt * 17 + ki) * 512);
      acc[mt][0] = __builtin_amdgcn_mfma_f32_16x16x32_bf16(a, bc, acc[mt][0], 0, 0, 0);
      acc[mt][1] = __builtin_amdgcn_mfma_f32_16x16x32_bf16(a, bc, acc[mt][1], 0, 0, 0);
    }
  }
  // nf chunks (Z rows 256..511): b128 tile reads (swizzled, ~conflict-free)
#pragma unroll
  for (int ck = 0; ck < 8; ++ck) {
    short8 bn0 = *(const short8*)tile_ptr(s_tile, 32 * w + ln15, (4 * ck + q) << 2);
    short8 bn1 = *(const short8*)tile_ptr(s_tile, 32 * w + 16 + ln15, (4 * ck + q) << 2);
#pragma unroll
    for (int mt = 0; mt < 4; ++mt) {
      short8 a = *(const short8*)(w1m_l + (size_t)(mt * 17 + 8 + ck) * 512);
      acc[mt][0] = __builtin_amdgcn_mfma_f32_16x16x32_bf16(a, bn0, acc[mt][0], 0, 0, 0);
      acc[mt][1] = __builtin_amdgcn_mfma_f32_16x16x32_bf16(a, bn1, acc[mt][1], 0, 0, 0);
    }
  }
  // edge chunk (Z rows 512..515; A rows >=516 are zero -> B tail don't-care)
  {
    union { unsigned u[4]; short8 s; } ub0, ub1;
    *(uint2*)&ub0.u[0] = *(const uint2*)&s_edge[w][ln15][0];
    ub0.u[2] = 0u; ub0.u[3] = 0u;
    *(uint2*)&ub1.u[0] = *(const uint2*)&s_edge[w][16 + ln15][0];
    ub1.u[2] = 0u; ub1.u[3] = 0u;
#pragma unroll
    for (int mt = 0; mt < 4; ++mt) {
      short8 a = *(const short8*)(w1m_l + (size_t)(mt * 17 + 16) * 512);
      acc[mt][0] = __builtin_amdgcn_mfma_f32_16x16x32_bf16(a, ub0.s, acc[mt][0], 0, 0, 0);
      acc[mt][1] = __builtin_amdgcn_mfma_f32_16x16x32_bf16(a, ub1.s, acc[mt][1], 0, 0, 0);
    }
  }

  // ---- Phase 3: relu, dot w2, fold rows -> logit per column n
#pragma unroll
  for (int nti = 0; nti < 2; ++nti) {
    float lp = 0.f;
#pragma unroll
    for (int mt = 0; mt < 4; ++mt) {
      const floatx4 w2v = *(const floatx4*)&s_w2v[mt * 16 + q * 4];
#pragma unroll
      for (int r = 0; r < 4; ++r)
        lp = fmaf(fmaxf(acc[mt][nti][r], 0.f), w2v[r], lp);
    }
    lp += __shfl_xor(lp, 16);
    lp += __shfl_xor(lp, 32);
    if (lane < 16) s_lg[(2 * w + nti) * 16 + ln15] = lp;
  }
  __syncthreads();

  // ---- Phase 4: masked softmax per p over K=32 (threads 0..127)
  if (t < 128) {
    float lg = s_lg[t];
    bool v = my_valid > 0.5f;
    float ml = v ? lg : -INFINITY;
#pragma unroll
    for (int m = 1; m < 32; m <<= 1) ml = fmaxf(ml, __shfl_xor(ml, m));
    float e = v ? __expf(lg - ml) : 0.f;
    float ssum = e;
#pragma unroll
    for (int m = 1; m < 32; m <<= 1) ssum += __shfl_xor(ssum, m);
    s_wt[t] = (ml > -INFINITY) ? (e / ssum) : 0.f;
  }
  __syncthreads();

  // ---- Phase 5: pooling. Thread t -> (cpr = t&127, p-pair ph = t>>7).
  {
    const int cpr = t & 127, ph = t >> 7;
    const int nb = ph * 64;  // n base for p_local = 2ph
    float a0e = 0.f, a0o = 0.f, a1e = 0.f, a1o = 0.f;
#pragma unroll
    for (int k = 0; k < K_; ++k) {
      const unsigned u0 = *tile_ptr(s_tile, nb + k, cpr);
      const unsigned u1 = *tile_ptr(s_tile, nb + 32 + k, cpr);
      const float wt0 = s_wt[nb + k];
      const float wt1 = s_wt[nb + 32 + k];
      a0e = fmaf(__uint_as_float(u0 << 16), wt0, a0e);
      a0o = fmaf(__uint_as_float(u0 & 0xffff0000u), wt0, a0o);
      a1e = fmaf(__uint_as_float(u1 << 16), wt1, a1e);
      a1o = fmaf(__uint_as_float(u1 & 0xffff0000u), wt1, a1o);
    }
    float* op = out + ((size_t)b * H_ + 2 * cpr) * P_ + p0 + 2 * ph;
    float2 ve; ve.x = a0e; ve.y = a1e;   // c even: p_local = 2ph, 2ph+1
    float2 vo; vo.x = a0o; vo.y = a1o;   // c odd
    *(float2*)op = ve;
    *(float2*)(op + P_) = vo;
  }
}

extern "C" void kernel_launch(void* const* d_in, const int* in_sizes, int n_in,
                              void* d_out, int out_size, void* d_ws,
                              size_t ws_size, hipStream_t stream) {
  const float* cur = (const float*)d_in[0];
  const float* nf  = (const float*)d_in[1];
  const float* nv  = (const float*)d_in[2];
  const float* ef  = (const float*)d_in[3];
  const float* w1  = (const float*)d_in[4];
  const float* b1  = (const float*)d_in[5];
  const float* w2  = (const float*)d_in[6];
  // d_in[7] = b2: softmax shift-invariant -> never affects output.

  unsigned short* w1m = (unsigned short*)d_ws;  // 34816 bf16 = 68 KB
  prep_kernel<<<(4 * 17 * 64 * 8 + 255) / 256, 256, 0, stream>>>(w1, w1m);
  soft_attn_agg_kernel<<<B_ * P_ / 4, 256, 0, stream>>>(
      cur, nf, nv, ef, w1m, b1, w2, (float*)d_out);
}

// Round 3
// 396.979 us; speedup vs baseline: 1.0887x; 1.0067x over previous
//
#include <hip/hip_runtime.h>
#include <math.h>

// SoftAttentionAggregator — round 8: register-staged phase 1, depth 8.
//
// Accounting: dur = 2x 1-GiB fills (~320 us, structural — present even when
// d_ws is unused) + prep (~2) + main (~77). Only main is addressable; floor
// ~30-40 us (FETCH 140-152 MB).
// Round-2 -> round-3 change: phase 1 dropped the fp32 LDS round-trip
// (global_load_lds -> s_raw -> ds_read -> pack -> ds_write). Now: 4 plain
// global_load_dword per wave-chunk into registers (256 B contiguous/instr,
// same DRAM address set), pack in regs, ds_write directly to the swizzled
// tile. Register staging gives compiler-SSA-counted vmcnt waits (impossible
// with global_load_lds) and pipeline depth 8 (32 VGPR) instead of 3 (LDS-
// capped). Staging (cur/nv/ef/b1/w2) loads issue BEFORE the chunk prologue
// so their consumes retire only their own (oldest) loads, never draining the
// chunk queue. sched_barrier(0) per iteration pins the issue-ahead shape.
// s_raw deleted: LDS 81,472 -> 70,208 B, still 2 blocks/CU.

#define B_ 8
#define H_ 256
#define P_ 1024
#define K_ 32
#define E_ 4
#define BN_ 64

typedef __attribute__((ext_vector_type(8))) short short8;
typedef __attribute__((ext_vector_type(4))) float floatx4;

__device__ __forceinline__ unsigned short bf16_rne(float f) {
  unsigned u = __float_as_uint(f);
  u += 0x7fffu + ((u >> 16) & 1u);
  return (unsigned short)(u >> 16);
}
// HW packed f32->bf16 RNE: D[15:0]=cvt(lo), D[31:16]=cvt(hi).
__device__ __forceinline__ unsigned pack_bf16(float lo, float hi) {
  unsigned r;
  asm("v_cvt_pk_bf16_f32 %0, %1, %2" : "=v"(r) : "v"(lo), "v"(hi));
  return r;
}

// Swizzled tile addressing: logical (n, cp) -> dword index.
// Row stride 128 dwords; 4-dword granule g = cp>>2 is XOR'd with (n&7).
// - GEMM b128 reads (granule-aligned): 2-way max (free).
// - pooling reads (consecutive cp per lane): conflict-free.
// - phase-1 column writes (n = lane): 8-way (small, off critical path).
__device__ __forceinline__ unsigned* tile_ptr(unsigned* tile, int n, int cp) {
  return tile + n * 128 + ((((cp >> 2) ^ (n & 7)) << 2) | (cp & 3));
}

// Pack w1 (64x516) into bf16 MFMA A-frag layout:
// idx = ((mt*17 + ki)*64 + lane)*8 + j ; o = mt*16 + (lane&15),
// c = ki*32 + (lane>>4)*8 + j ; zero-pad c >= 516.
__global__ __launch_bounds__(256) void prep_kernel(
    const float* __restrict__ w1, unsigned short* __restrict__ w1m) {
  int i = blockIdx.x * 256 + threadIdx.x;
  if (i >= 4 * 17 * 64 * 8) return;  // 34816
  int j = i & 7, lane = (i >> 3) & 63;
  int kt = i >> 9;
  int mt = kt / 17, ki = kt % 17;
  int o = mt * 16 + (lane & 15);
  int c = ki * 32 + (lane >> 4) * 8 + j;
  float v = (c < 516) ? w1[o * 516 + c] : 0.f;
  w1m[i] = bf16_rne(v);
}

__global__ __launch_bounds__(256, 2) void soft_attn_agg_kernel(
    const float* __restrict__ cur,   // (B,H,P)
    const float* __restrict__ nf,    // (B,H,P,K)
    const float* __restrict__ nv,    // (B,1,P,K)
    const float* __restrict__ ef,    // (B,E,P,K)
    const unsigned short* __restrict__ w1m,  // packed A-frags (68 KB, L2-hot)
    const float* __restrict__ b1,    // (64)
    const float* __restrict__ w2,    // (64)
    float* __restrict__ out) {       // (B,H,P)
  __shared__ unsigned s_tile[128 * 128];     // 64 KB bf16 c-pair tile, swizzled
  __shared__ unsigned short s_curb[4][264];  // bf16 cur [pl][c]
  __shared__ unsigned s_edge[4][32][2];      // [pl][k][e01,e23]
  __shared__ float s_b1v[BN_];
  __shared__ float s_w2v[BN_];
  __shared__ float s_lg[128];
  __shared__ float s_wt[128];

  const int t = threadIdx.x;
  const unsigned bid = blockIdx.x;
  const unsigned xcd = bid & 7u, sx = bid >> 3;
  const int b = (int)(sx >> 5);
  const int pg = (int)(xcd * 32u + (sx & 31u));  // 0..255
  const int p0 = pg * 4;

  const int w = t >> 6;     // wave 0..3
  const int lane = t & 63;
  const int q = lane >> 4;  // quad
  const int ln15 = lane & 15;

  const int PKr = P_ * K_;
  const float* nf_b = nf + ((size_t)b * H_ * P_ + p0) * K_;

  // ---- (a) staging loads FIRST (oldest in the vmcnt queue) ----
  float4 ca = *(const float4*)(cur + ((size_t)b * H_ + t) * P_ + p0);
  float sv = 0.f, e0 = 0.f, e1 = 0.f, e2 = 0.f, e3 = 0.f, bw = 0.f;
  if (t < 128) {
    sv = nv[((size_t)b * P_ + p0) * K_ + t];
    const int pl = t >> 5, k = t & 31;
    const float* ep = ef + ((size_t)b * E_ * P_ + p0 + pl) * K_ + k;
    e0 = ep[0];
    e1 = ep[(size_t)PKr];
    e2 = ep[(size_t)(2 * PKr)];
    e3 = ep[(size_t)(3 * PKr)];
  } else if (t < 192) {
    bw = b1[t - 128];
  } else {
    bw = w2[t - 192];
  }

  // ---- (b) phase-1 prologue: issue chunks 0..7 (depth 8) ----
  // Chunk ch covers c = 8ch..8ch+7; wave w owns c-pair cpv = 4ch+w, i.e.
  // rows c_e = 8ch+2w, c_o = c_e+1. Lane l covers n = l and l+64.
  float ve0[32], ve1[32], vo0[32], vo1[32];
#define ISSUE_CH(ch)                                       \
  {                                                        \
    const float* re = nf_b + (size_t)(8 * (ch) + 2 * w) * PKr; \
    const float* ro = re + PKr;                            \
    ve0[ch] = re[lane];                                    \
    ve1[ch] = re[lane + 64];                               \
    vo0[ch] = ro[lane];                                    \
    vo1[ch] = ro[lane + 64];                               \
  }
#define CONSUME_CH(ch)                                     \
  {                                                        \
    unsigned pk0 = pack_bf16(ve0[ch], vo0[ch]);            \
    unsigned pk1 = pack_bf16(ve1[ch], vo1[ch]);            \
    const int cpv = 4 * (ch) + w;                          \
    *tile_ptr(s_tile, lane, cpv) = pk0;                    \
    *tile_ptr(s_tile, lane + 64, cpv) = pk1;               \
  }

#pragma unroll
  for (int ch = 0; ch < 8; ++ch) ISSUE_CH(ch);
  __builtin_amdgcn_sched_barrier(0);

  // ---- (c) staging consumes (retire only the oldest, pre-chunk loads) ----
  s_curb[0][t] = bf16_rne(ca.x);
  s_curb[1][t] = bf16_rne(ca.y);
  s_curb[2][t] = bf16_rne(ca.z);
  s_curb[3][t] = bf16_rne(ca.w);
  float my_valid = sv;
  if (t < 128) {
    const int pl = t >> 5, k = t & 31;
    s_edge[pl][k][0] = pack_bf16(e0, e1);
    s_edge[pl][k][1] = pack_bf16(e2, e3);
  } else if (t < 192) {
    s_b1v[t - 128] = bw;
  } else {
    s_w2v[t - 192] = bw;
  }
  __builtin_amdgcn_sched_barrier(0);

  // ---- (d) steady pipeline: consume ch, issue ch+8 ----
#pragma unroll
  for (int ch = 0; ch < 32; ++ch) {
    if (ch < 24) ISSUE_CH(ch + 8);
    CONSUME_CH(ch);
    __builtin_amdgcn_sched_barrier(0);
  }
  __syncthreads();  // tile + curb/edge/b1/w2 complete for all waves

  // ---- Phase 2: GEMM hid[64 x 128] = W1[64x544] * Z[544x128] via
  // mfma_f32_16x16x32_bf16, A-frags from packed w1m (coalesced 1 KB loads).
  floatx4 acc[4][2];
#pragma unroll
  for (int mt = 0; mt < 4; ++mt) {
    floatx4 binit = *(const floatx4*)&s_b1v[mt * 16 + q * 4];
    acc[mt][0] = binit;
    acc[mt][1] = binit;
  }
  const unsigned short* w1m_l = w1m + (size_t)lane * 8;

  // cur chunks (Z rows 0..255): b-frag independent of k -> shared by both nt
#pragma unroll
  for (int ki = 0; ki < 8; ++ki) {
    short8 bc = *(const short8*)&s_curb[w][ki * 32 + q * 8];
#pragma unroll
    for (int mt = 0; mt < 4; ++mt) {
      short8 a = *(const short8*)(w1m_l + (size_t)(mt * 17 + ki) * 512);
      acc[mt][0] = __builtin_amdgcn_mfma_f32_16x16x32_bf16(a, bc, acc[mt][0], 0, 0, 0);
      acc[mt][1] = __builtin_amdgcn_mfma_f32_16x16x32_bf16(a, bc, acc[mt][1], 0, 0, 0);
    }
  }
  // nf chunks (Z rows 256..511): b128 tile reads (swizzled, ~conflict-free)
#pragma unroll
  for (int ck = 0; ck < 8; ++ck) {
    short8 bn0 = *(const short8*)tile_ptr(s_tile, 32 * w + ln15, (4 * ck + q) << 2);
    short8 bn1 = *(const short8*)tile_ptr(s_tile, 32 * w + 16 + ln15, (4 * ck + q) << 2);
#pragma unroll
    for (int mt = 0; mt < 4; ++mt) {
      short8 a = *(const short8*)(w1m_l + (size_t)(mt * 17 + 8 + ck) * 512);
      acc[mt][0] = __builtin_amdgcn_mfma_f32_16x16x32_bf16(a, bn0, acc[mt][0], 0, 0, 0);
      acc[mt][1] = __builtin_amdgcn_mfma_f32_16x16x32_bf16(a, bn1, acc[mt][1], 0, 0, 0);
    }
  }
  // edge chunk (Z rows 512..515; A rows >=516 are zero -> B tail don't-care)
  {
    union { unsigned u[4]; short8 s; } ub0, ub1;
    *(uint2*)&ub0.u[0] = *(const uint2*)&s_edge[w][ln15][0];
    ub0.u[2] = 0u; ub0.u[3] = 0u;
    *(uint2*)&ub1.u[0] = *(const uint2*)&s_edge[w][16 + ln15][0];
    ub1.u[2] = 0u; ub1.u[3] = 0u;
#pragma unroll
    for (int mt = 0; mt < 4; ++mt) {
      short8 a = *(const short8*)(w1m_l + (size_t)(mt * 17 + 16) * 512);
      acc[mt][0] = __builtin_amdgcn_mfma_f32_16x16x32_bf16(a, ub0.s, acc[mt][0], 0, 0, 0);
      acc[mt][1] = __builtin_amdgcn_mfma_f32_16x16x32_bf16(a, ub1.s, acc[mt][1], 0, 0, 0);
    }
  }

  // ---- Phase 3: relu, dot w2, fold rows -> logit per column n
#pragma unroll
  for (int nti = 0; nti < 2; ++nti) {
    float lp = 0.f;
#pragma unroll
    for (int mt = 0; mt < 4; ++mt) {
      const floatx4 w2v = *(const floatx4*)&s_w2v[mt * 16 + q * 4];
#pragma unroll
      for (int r = 0; r < 4; ++r)
        lp = fmaf(fmaxf(acc[mt][nti][r], 0.f), w2v[r], lp);
    }
    lp += __shfl_xor(lp, 16);
    lp += __shfl_xor(lp, 32);
    if (lane < 16) s_lg[(2 * w + nti) * 16 + ln15] = lp;
  }
  __syncthreads();

  // ---- Phase 4: masked softmax per p over K=32 (threads 0..127)
  if (t < 128) {
    float lg = s_lg[t];
    bool v = my_valid > 0.5f;
    float ml = v ? lg : -INFINITY;
#pragma unroll
    for (int m = 1; m < 32; m <<= 1) ml = fmaxf(ml, __shfl_xor(ml, m));
    float e = v ? __expf(lg - ml) : 0.f;
    float ssum = e;
#pragma unroll
    for (int m = 1; m < 32; m <<= 1) ssum += __shfl_xor(ssum, m);
    s_wt[t] = (ml > -INFINITY) ? (e / ssum) : 0.f;
  }
  __syncthreads();

  // ---- Phase 5: pooling. Thread t -> (cpr = t&127, p-pair ph = t>>7).
  {
    const int cpr = t & 127, ph = t >> 7;
    const int nb = ph * 64;  // n base for p_local = 2ph
    float a0e = 0.f, a0o = 0.f, a1e = 0.f, a1o = 0.f;
#pragma unroll
    for (int k = 0; k < K_; ++k) {
      const unsigned u0 = *tile_ptr(s_tile, nb + k, cpr);
      const unsigned u1 = *tile_ptr(s_tile, nb + 32 + k, cpr);
      const float wt0 = s_wt[nb + k];
      const float wt1 = s_wt[nb + 32 + k];
      a0e = fmaf(__uint_as_float(u0 << 16), wt0, a0e);
      a0o = fmaf(__uint_as_float(u0 & 0xffff0000u), wt0, a0o);
      a1e = fmaf(__uint_as_float(u1 << 16), wt1, a1e);
      a1o = fmaf(__uint_as_float(u1 & 0xffff0000u), wt1, a1o);
    }
    float* op = out + ((size_t)b * H_ + 2 * cpr) * P_ + p0 + 2 * ph;
    float2 ve; ve.x = a0e; ve.y = a1e;   // c even: p_local = 2ph, 2ph+1
    float2 vo; vo.x = a0o; vo.y = a1o;   // c odd
    *(float2*)op = ve;
    *(float2*)(op + P_) = vo;
  }
}

extern "C" void kernel_launch(void* const* d_in, const int* in_sizes, int n_in,
                              void* d_out, int out_size, void* d_ws,
                              size_t ws_size, hipStream_t stream) {
  const float* cur = (const float*)d_in[0];
  const float* nf  = (const float*)d_in[1];
  const float* nv  = (const float*)d_in[2];
  const float* ef  = (const float*)d_in[3];
  const float* w1  = (const float*)d_in[4];
  const float* b1  = (const float*)d_in[5];
  const float* w2  = (const float*)d_in[6];
  // d_in[7] = b2: softmax shift-invariant -> never affects output.

  unsigned short* w1m = (unsigned short*)d_ws;  // 34816 bf16 = 68 KB
  prep_kernel<<<(4 * 17 * 64 * 8 + 255) / 256, 256, 0, stream>>>(w1, w1m);
  soft_attn_agg_kernel<<<B_ * P_ / 4, 256, 0, stream>>>(
      cur, nf, nv, ef, w1m, b1, w2, (float*)d_out);
}

// Round 5
// 396.020 us; speedup vs baseline: 1.0913x; 1.0024x over previous
//
#include <hip/hip_runtime.h>
#include <math.h>

// SoftAttentionAggregator — round 9 (resubmit; round-4 bench was an infra
// failure, no code change): p=2 per block, 4 blocks/CU.
//
// Accounting: dur = 2x 1-GiB structural fills (~320 us) + prep (~2) + main.
// Main ~75 us vs ~46 us memory floor. Rounds 6-8 showed per-wave pipeline
// depth is NOT the limiter (depth 3->8 bought ~2 us). Remaining gap theory:
// 2 blocks/CU means HBM idles whenever both resident blocks are in the
// barrier-separated compute phases, + 4-generation tail. Fix: halve the
// block's p-extent (p=2, 4096 blocks), tile 64n x 128cp = 32 KB, LDS ~36 KB
// -> 4 blocks/CU (16 waves/CU). W1 reuse per block would halve, so the GEMM
// is repartitioned per-wave-mt: wave w computes hid rows 16w..16w+15 over
// ALL 64 n-columns; each block reads each w1m frag exactly once (68 KB) ->
// w1m L2/XCD ~35 MB, off critical path. Logits: per-wave partial row-fold
// into s_lgp[w][n], barrier, threads<64 sum 4 partials -> softmax.
// Phase-1: same register-staged depth-8 pipeline (2 loads/chunk at p=2).

#define B_ 8
#define H_ 256
#define P_ 1024
#define K_ 32
#define E_ 4
#define BN_ 64

typedef __attribute__((ext_vector_type(8))) short short8;
typedef __attribute__((ext_vector_type(4))) float floatx4;

__device__ __forceinline__ unsigned short bf16_rne(float f) {
  unsigned u = __float_as_uint(f);
  u += 0x7fffu + ((u >> 16) & 1u);
  return (unsigned short)(u >> 16);
}
// HW packed f32->bf16 RNE: D[15:0]=cvt(lo), D[31:16]=cvt(hi).
__device__ __forceinline__ unsigned pack_bf16(float lo, float hi) {
  unsigned r;
  asm("v_cvt_pk_bf16_f32 %0, %1, %2" : "=v"(r) : "v"(lo), "v"(hi));
  return r;
}

// Swizzled tile addressing: logical (n, cp) -> dword index.
// Row stride 128 dwords; 4-dword granule g = cp>>2 is XOR'd with (n&7).
// - GEMM b128 reads (granule-aligned): distinct dwords, ~2-way max (free).
// - pooling reads (consecutive cp per lane): 2-way (free).
// - phase-1 column writes (n = lane): 8-way (small, off critical path).
__device__ __forceinline__ unsigned* tile_ptr(unsigned* tile, int n, int cp) {
  return tile + n * 128 + ((((cp >> 2) ^ (n & 7)) << 2) | (cp & 3));
}

// Pack w1 (64x516) into bf16 MFMA A-frag layout:
// idx = ((mt*17 + ki)*64 + lane)*8 + j ; o = mt*16 + (lane&15),
// c = ki*32 + (lane>>4)*8 + j ; zero-pad c >= 516.
__global__ __launch_bounds__(256) void prep_kernel(
    const float* __restrict__ w1, unsigned short* __restrict__ w1m) {
  int i = blockIdx.x * 256 + threadIdx.x;
  if (i >= 4 * 17 * 64 * 8) return;  // 34816
  int j = i & 7, lane = (i >> 3) & 63;
  int kt = i >> 9;
  int mt = kt / 17, ki = kt % 17;
  int o = mt * 16 + (lane & 15);
  int c = ki * 32 + (lane >> 4) * 8 + j;
  float v = (c < 516) ? w1[o * 516 + c] : 0.f;
  w1m[i] = bf16_rne(v);
}

__global__ __launch_bounds__(256, 4) void soft_attn_agg_kernel(
    const float* __restrict__ cur,   // (B,H,P)
    const float* __restrict__ nf,    // (B,H,P,K)
    const float* __restrict__ nv,    // (B,1,P,K)
    const float* __restrict__ ef,    // (B,E,P,K)
    const unsigned short* __restrict__ w1m,  // packed A-frags (68 KB, L2-hot)
    const float* __restrict__ b1,    // (64)
    const float* __restrict__ w2,    // (64)
    float* __restrict__ out) {       // (B,H,P)
  __shared__ unsigned s_tile[64 * 128];      // 32 KB bf16 c-pair tile, swizzled
  __shared__ unsigned short s_curb[2][264];  // bf16 cur [pl][c]
  __shared__ unsigned s_edge[2][32][2];      // [pl][k][e01,e23]
  __shared__ float s_b1v[BN_];
  __shared__ float s_w2v[BN_];
  __shared__ float s_lgp[4][64];             // per-wave logit partials
  __shared__ float s_wt[64];

  const int t = threadIdx.x;
  const unsigned bid = blockIdx.x;
  const unsigned xcd = bid & 7u, sx = bid >> 3;  // sx 0..511
  const int b = (int)(sx >> 6);
  const int pg = (int)(xcd * 64u + (sx & 63u));  // 0..511
  const int p0 = pg * 2;

  const int w = t >> 6;     // wave 0..3
  const int lane = t & 63;
  const int q = lane >> 4;  // quad
  const int ln15 = lane & 15;

  const int PKr = P_ * K_;
  const float* nf_b = nf + ((size_t)b * H_ * P_ + p0) * K_;

  // ---- (a) staging loads FIRST (oldest in the vmcnt queue) ----
  float2 ca = *(const float2*)(cur + ((size_t)b * H_ + t) * P_ + p0);
  float sv = 0.f, e0 = 0.f, e1 = 0.f, e2 = 0.f, e3 = 0.f, bw = 0.f;
  if (t < 64) {
    sv = nv[((size_t)b * P_ + p0) * K_ + t];  // 2 p x 32 k contiguous
    const int pl = t >> 5, k = t & 31;
    const float* ep = ef + ((size_t)b * E_ * P_ + p0 + pl) * K_ + k;
    e0 = ep[0];
    e1 = ep[(size_t)PKr];
    e2 = ep[(size_t)(2 * PKr)];
    e3 = ep[(size_t)(3 * PKr)];
  } else if (t < 128) {
    bw = b1[t - 64];
  } else if (t < 192) {
    bw = w2[t - 128];
  }

  // ---- (b) phase-1 prologue: issue chunks 0..7 (depth 8) ----
  // Chunk ch: wave w owns c-pair cpv = 4ch+w, rows c_e = 8ch+2w, c_o = +1.
  // Row = 2p x 32k = 256 B = 64 lanes x 4 B; lane l holds n = l.
  float ve[32], vo[32];
#define ISSUE_CH(ch)                                           \
  {                                                            \
    const float* re = nf_b + (size_t)(8 * (ch) + 2 * w) * PKr; \
    ve[ch] = re[lane];                                         \
    vo[ch] = re[PKr + lane];                                   \
  }
#define CONSUME_CH(ch)                                         \
  {                                                            \
    unsigned pk = pack_bf16(ve[ch], vo[ch]);                   \
    *tile_ptr(s_tile, lane, 4 * (ch) + w) = pk;                \
  }

#pragma unroll
  for (int ch = 0; ch < 8; ++ch) ISSUE_CH(ch);
  __builtin_amdgcn_sched_barrier(0);

  // ---- (c) staging consumes (retire only the oldest, pre-chunk loads) ----
  s_curb[0][t] = bf16_rne(ca.x);
  s_curb[1][t] = bf16_rne(ca.y);
  float my_valid = sv;
  if (t < 64) {
    s_edge[t >> 5][t & 31][0] = pack_bf16(e0, e1);
    s_edge[t >> 5][t & 31][1] = pack_bf16(e2, e3);
  } else if (t < 128) {
    s_b1v[t - 64] = bw;
  } else if (t < 192) {
    s_w2v[t - 128] = bw;
  }
  __builtin_amdgcn_sched_barrier(0);

  // ---- (d) steady pipeline: consume ch, issue ch+8 ----
#pragma unroll
  for (int ch = 0; ch < 32; ++ch) {
    if (ch < 24) ISSUE_CH(ch + 8);
    CONSUME_CH(ch);
    __builtin_amdgcn_sched_barrier(0);
  }
  __syncthreads();  // tile + curb/edge/b1/w2 complete for all waves

  // ---- Phase 2: GEMM hid[64 x 64] = W1[64x544] * Z[544x64].
  // Per-wave mt = w: wave w computes hid rows 16w..16w+15 for ALL n
  // (4 n-tiles) -> each w1m frag read once per block (68 KB total).
  floatx4 acc[4];
  {
    const floatx4 binit = *(const floatx4*)&s_b1v[16 * w + 4 * q];
    acc[0] = binit; acc[1] = binit; acc[2] = binit; acc[3] = binit;
  }
  const unsigned short* w1m_w = w1m + (size_t)(w * 17) * 512 + (size_t)lane * 8;

  // cur chunks (Z rows 0..255): B-frag depends on n only via pl = nt>>1.
#pragma unroll
  for (int ki = 0; ki < 8; ++ki) {
    short8 a = *(const short8*)(w1m_w + (size_t)ki * 512);
    short8 bc0 = *(const short8*)&s_curb[0][ki * 32 + q * 8];
    short8 bc1 = *(const short8*)&s_curb[1][ki * 32 + q * 8];
    acc[0] = __builtin_amdgcn_mfma_f32_16x16x32_bf16(a, bc0, acc[0], 0, 0, 0);
    acc[1] = __builtin_amdgcn_mfma_f32_16x16x32_bf16(a, bc0, acc[1], 0, 0, 0);
    acc[2] = __builtin_amdgcn_mfma_f32_16x16x32_bf16(a, bc1, acc[2], 0, 0, 0);
    acc[3] = __builtin_amdgcn_mfma_f32_16x16x32_bf16(a, bc1, acc[3], 0, 0, 0);
  }
  // nf chunks (Z rows 256..511): b128 tile reads (swizzled).
#pragma unroll
  for (int ck = 0; ck < 8; ++ck) {
    short8 a = *(const short8*)(w1m_w + (size_t)(8 + ck) * 512);
#pragma unroll
    for (int nt = 0; nt < 4; ++nt) {
      short8 bn = *(const short8*)tile_ptr(s_tile, 16 * nt + ln15, (4 * ck + q) << 2);
      acc[nt] = __builtin_amdgcn_mfma_f32_16x16x32_bf16(a, bn, acc[nt], 0, 0, 0);
    }
  }
  // edge chunk (Z rows 512..515; A rows >=516 zero -> B tail don't-care).
  {
    short8 ae = *(const short8*)(w1m_w + (size_t)16 * 512);
#pragma unroll
    for (int nt = 0; nt < 4; ++nt) {
      union { unsigned u[4]; short8 s; } ub;
      *(uint2*)&ub.u[0] = *(const uint2*)&s_edge[nt >> 1][(nt & 1) * 16 + ln15][0];
      ub.u[2] = 0u; ub.u[3] = 0u;
      acc[nt] = __builtin_amdgcn_mfma_f32_16x16x32_bf16(ae, ub.s, acc[nt], 0, 0, 0);
    }
  }

  // ---- Phase 3: relu, dot w2 over own 16 rows -> per-wave logit partials
  {
    const floatx4 w2v = *(const floatx4*)&s_w2v[16 * w + 4 * q];
#pragma unroll
    for (int nt = 0; nt < 4; ++nt) {
      float lp = 0.f;
#pragma unroll
      for (int r = 0; r < 4; ++r)
        lp = fmaf(fmaxf(acc[nt][r], 0.f), w2v[r], lp);
      lp += __shfl_xor(lp, 16);
      lp += __shfl_xor(lp, 32);
      if (lane < 16) s_lgp[w][16 * nt + ln15] = lp;
    }
  }
  __syncthreads();

  // ---- Phase 4: sum wave partials + masked softmax over K=32 (t<64)
  if (t < 64) {
    float lg = s_lgp[0][t] + s_lgp[1][t] + s_lgp[2][t] + s_lgp[3][t];
    bool v = my_valid > 0.5f;
    float ml = v ? lg : -INFINITY;
#pragma unroll
    for (int m = 1; m < 32; m <<= 1) ml = fmaxf(ml, __shfl_xor(ml, m));
    float e = v ? __expf(lg - ml) : 0.f;
    float ssum = e;
#pragma unroll
    for (int m = 1; m < 32; m <<= 1) ssum += __shfl_xor(ssum, m);
    s_wt[t] = (ml > -INFINITY) ? (e / ssum) : 0.f;
  }
  __syncthreads();

  // ---- Phase 5: pooling. Thread t -> (cpr = t&127, p_local ph = t>>7).
  {
    const int cpr = t & 127, ph = t >> 7;
    const int nb = 32 * ph;
    float a_e = 0.f, a_o = 0.f;
#pragma unroll
    for (int k = 0; k < K_; ++k) {
      const unsigned u = *tile_ptr(s_tile, nb + k, cpr);
      const float wt = s_wt[nb + k];
      a_e = fmaf(__uint_as_float(u << 16), wt, a_e);
      a_o = fmaf(__uint_as_float(u & 0xffff0000u), wt, a_o);
    }
    float* op = out + ((size_t)b * H_ + 2 * cpr) * P_ + p0 + ph;
    *op = a_e;          // c even = 2*cpr
    *(op + P_) = a_o;   // c odd  = 2*cpr+1
  }
}

extern "C" void kernel_launch(void* const* d_in, const int* in_sizes, int n_in,
                              void* d_out, int out_size, void* d_ws,
                              size_t ws_size, hipStream_t stream) {
  const float* cur = (const float*)d_in[0];
  const float* nf  = (const float*)d_in[1];
  const float* nv  = (const float*)d_in[2];
  const float* ef  = (const float*)d_in[3];
  const float* w1  = (const float*)d_in[4];
  const float* b1  = (const float*)d_in[5];
  const float* w2  = (const float*)d_in[6];
  // d_in[7] = b2: softmax shift-invariant -> never affects output.

  unsigned short* w1m = (unsigned short*)d_ws;  // 34816 bf16 = 68 KB
  prep_kernel<<<(4 * 17 * 64 * 8 + 255) / 256, 256, 0, stream>>>(w1, w1m);
  soft_attn_agg_kernel<<<B_ * P_ / 2, 256, 0, stream>>>(
      cur, nf, nv, ef, w1m, b1, w2, (float*)d_out);
}